// Round 1
// baseline (5578.506 us; speedup 1.0000x reference)
//
#include <hip/hip_runtime.h>

typedef __bf16 bf16x8 __attribute__((ext_vector_type(8)));
typedef float f32x4 __attribute__((ext_vector_type(4)));

__device__ __forceinline__ unsigned short f2bf(float f) {
  union { float f; unsigned u; } v; v.f = f;
  unsigned r = v.u + 0x7FFFu + ((v.u >> 16) & 1u);
  return (unsigned short)(r >> 16);
}

__device__ __forceinline__ float wred2(float v) {
#pragma unroll
  for (int o = 32; o > 0; o >>= 1) v += __shfl_down(v, o);
  return v;
}

// ---------------------------------------------------------------- convert
__global__ __launch_bounds__(256) void f2bf4(const float* __restrict__ s,
                                             unsigned short* __restrict__ d, int n4) {
  int i = blockIdx.x * 256 + threadIdx.x;
  if (i >= n4) return;
  float4 v = ((const float4*)s)[i];
  ushort4 o = make_ushort4(f2bf(v.x), f2bf(v.y), f2bf(v.z), f2bf(v.w));
  ((ushort4*)d)[i] = o;
}

// ---------------------------------------------------------------- expand: z = x@W^T+b, LN, relu
__global__ __launch_bounds__(256) void expand_k(
    const float* __restrict__ x, const float* __restrict__ Wexp,
    const float* __restrict__ bexp, const float* __restrict__ g1,
    const float* __restrict__ be1,
    float* __restrict__ expanded, unsigned short* __restrict__ h0b) {
  const int b = blockIdx.x, tid = threadIdx.x;
  __shared__ float4 xsh[128];
  __shared__ float r1[4], r2[4];
  if (tid < 128) xsh[tid] = ((const float4*)(x + b * 512))[tid];
  __syncthreads();
  float za[4];
  float s1 = 0.f, s2 = 0.f;
#pragma unroll
  for (int i = 0; i < 4; ++i) {
    int j = tid + i * 256;
    const float4* wr = (const float4*)(Wexp + (size_t)j * 512);
    float acc = bexp[j];
    for (int k = 0; k < 128; ++k) {
      float4 xv = xsh[k], wv = wr[k];
      acc += xv.x * wv.x + xv.y * wv.y + xv.z * wv.z + xv.w * wv.w;
    }
    za[i] = acc; s1 += acc; s2 += acc * acc;
  }
  s1 = wred2(s1); s2 = wred2(s2);
  if ((tid & 63) == 0) { r1[tid >> 6] = s1; r2[tid >> 6] = s2; }
  __syncthreads();
  float t1 = r1[0] + r1[1] + r1[2] + r1[3];
  float t2 = r2[0] + r2[1] + r2[2] + r2[3];
  float mu = t1 * (1.f / 1024.f);
  float var = t2 * (1.f / 1024.f) - mu * mu;
  float rs = rsqrtf(var + 1e-5f);
#pragma unroll
  for (int i = 0; i < 4; ++i) {
    int j = tid + i * 256;
    float v = fmaxf((za[i] - mu) * rs * g1[j] + be1[j], 0.f);
    expanded[(size_t)b * 1024 + j] = v;
    h0b[(size_t)b * 1024 + j] = f2bf(v);
  }
}

// ---------------------------------------------------------------- xs[t*32+b][k] = bf16(expanded[b][k]+pos[t][k]); zero barriers
__global__ __launch_bounds__(256) void build_xs_k(
    const float* __restrict__ expanded, const float* __restrict__ pos,
    unsigned short* __restrict__ xs, int* __restrict__ bars) {
  int i = blockIdx.x * 256 + threadIdx.x;
  if (blockIdx.x == 0 && threadIdx.x < 64) bars[threadIdx.x] = 0;
  int e = i << 2;
  int row = e >> 10, k = e & 1023;
  int tt = row >> 5, bb = row & 31;
  float4 ev = *(const float4*)(expanded + (size_t)bb * 1024 + k);
  float4 pv = *(const float4*)(pos + (size_t)tt * 1024 + k);
  ushort4 o = make_ushort4(f2bf(ev.x + pv.x), f2bf(ev.y + pv.y),
                           f2bf(ev.z + pv.z), f2bf(ev.w + pv.w));
  *(ushort4*)(xs + (size_t)row * 1024 + k) = o;
}

// ---------------------------------------------------------------- bf16 MFMA GEMM: C = A @ W^T (+epilogue)
// A: [M,K] bf16 rowmajor, W: [N,K] bf16 rowmajor. M%128==0, N%128==0, K%64==0.
#define BM 128
#define BN 128
#define BKK 64
#define LDKP 72   // +8 pad: rows shift 4 banks -> uniform 2 lanes/bank on ds_read_b128

template<int EPI>
__global__ __launch_bounds__(256) void gemm_bt(
    const unsigned short* __restrict__ A, const unsigned short* __restrict__ W,
    int M, int N, int K,
    const float* __restrict__ bias0, const float* __restrict__ bias1,
    float* __restrict__ out) {
  __shared__ __align__(16) unsigned short As[BM * LDKP];
  __shared__ __align__(16) unsigned short Bs[BN * LDKP];
  const int tid = threadIdx.x;
  const int lane = tid & 63;
  const int w = tid >> 6;
  const int wm = (w & 1) * 64;
  const int wn = (w >> 1) * 64;
  const int m0 = blockIdx.x * BM;
  const int n0 = blockIdx.y * BN;
  const int srow = tid >> 3;
  const int scol = (tid & 7) * 8;
  const int c = lane & 15;
  const int q8 = (lane >> 4) * 8;
  f32x4 acc[4][4] = {};
  for (int k0 = 0; k0 < K; k0 += BKK) {
#pragma unroll
    for (int p = 0; p < 4; ++p) {
      int r = p * 32 + srow;
      *(uint4*)&As[r * LDKP + scol] = *(const uint4*)&A[(size_t)(m0 + r) * K + k0 + scol];
      *(uint4*)&Bs[r * LDKP + scol] = *(const uint4*)&W[(size_t)(n0 + r) * K + k0 + scol];
    }
    __syncthreads();
#pragma unroll
    for (int kk = 0; kk < BKK; kk += 32) {
      bf16x8 af[4], bb[4];
#pragma unroll
      for (int i = 0; i < 4; ++i)
        af[i] = *(const bf16x8*)&As[(wm + i * 16 + c) * LDKP + kk + q8];
#pragma unroll
      for (int j = 0; j < 4; ++j)
        bb[j] = *(const bf16x8*)&Bs[(wn + j * 16 + c) * LDKP + kk + q8];
#pragma unroll
      for (int i = 0; i < 4; ++i)
#pragma unroll
        for (int j = 0; j < 4; ++j)
          acc[i][j] = __builtin_amdgcn_mfma_f32_16x16x32_bf16(af[i], bb[j], acc[i][j], 0, 0, 0);
    }
    __syncthreads();
  }
  const int q = lane >> 4;
#pragma unroll
  for (int i = 0; i < 4; ++i) {
#pragma unroll
    for (int j = 0; j < 4; ++j) {
#pragma unroll
      for (int r = 0; r < 4; ++r) {
        int m = m0 + wm + i * 16 + q * 4 + r;
        int n = n0 + wn + j * 16 + c;
        float v = acc[i][j][r];
        if (EPI == 0) {            // G epilogue: +bih+bhh, [dir][m][j] layout
          v += bias0[n] + bias1[n];
          int dir = n >> 10, jj = n & 1023;
          out[(size_t)dir * M * 1024 + (size_t)m * 1024 + jj] = v;
        } else if (EPI == 1) {     // plain [M,N] + bias
          v += bias0[n];
          out[(size_t)m * N + n] = v;
        } else {                   // head: row m = t*32+b -> out[b][t][n], +bp2
          v += bias0[n];
          int b = m & 31, t = m >> 5;
          out[(size_t)(b * 128 + t) * 32000 + n] = v;
        }
      }
    }
  }
}

// ---------------------------------------------------------------- cache-bypass h exchange
// h is written with agent-scope write-through stores (land at LLC, never dirty in
// per-XCD L2) and read with agent-scope bypass loads (never cached in L1/L2).
// => NO buffer_wbl2 / buffer_inv needed anywhere in the 128-step loop, and the
// read-only Whh/G stay L2-resident across all steps.
__device__ __forceinline__ bf16x8 ldh16(const unsigned short* p) {
  union { unsigned long long q[2]; bf16x8 v; } u;
  unsigned long long* pq = (unsigned long long*)p;
  u.q[0] = __hip_atomic_load(pq,     __ATOMIC_RELAXED, __HIP_MEMORY_SCOPE_AGENT);
  u.q[1] = __hip_atomic_load(pq + 1, __ATOMIC_RELAXED, __HIP_MEMORY_SCOPE_AGENT);
  return u.v;
}

__device__ __forceinline__ void sth(unsigned short* p, unsigned short v) {
  __hip_atomic_store(p, v, __ATOMIC_RELAXED, __HIP_MEMORY_SCOPE_AGENT);
}

// ---------------------------------------------------------------- grid barrier (monotonic counter, fence-free)
// All h stores are write-through (sc-flagged) so a per-wave vmcnt(0) drain is a
// full release; no L2 writeback/invalidate instructions are emitted.
__device__ __forceinline__ void gbar(int* bar, int nblocks, int phase) {
  asm volatile("s_waitcnt vmcnt(0)" ::: "memory");  // every wave drains its own stores
  __syncthreads();
  if (threadIdx.x == 0) {
    __hip_atomic_fetch_add(bar, 1, __ATOMIC_RELAXED, __HIP_MEMORY_SCOPE_AGENT);
    const int target = nblocks * phase;
    while (__hip_atomic_load(bar, __ATOMIC_RELAXED, __HIP_MEMORY_SCOPE_AGENT) < target)
      __builtin_amdgcn_s_sleep(2);
  }
  __syncthreads();
}

// ---------------------------------------------------------------- persistent bidirectional RNN layer
// h_new = relu(G[dir][t] + h @ Whh[dir]^T); xout[t][b][dir*1024+j] = h_new
// 32 blocks x 256 thr; wave = (mtile in 0..1) x (npair in 0..31 -> 2 n-tiles)
__global__ __launch_bounds__(256) void rnn_layer(
    const unsigned short* __restrict__ h0,     // [32][1024] bf16
    const unsigned short* __restrict__ Whh,    // [2][1024][1024] bf16
    const float* __restrict__ G,               // [2][4096][1024] fp32, row=t*32+b
    unsigned short* __restrict__ xout,         // [4096][2048] bf16, row=t*32+b
    unsigned short* __restrict__ hbuf,         // [2][2][32][1024] bf16 ping-pong
    int* __restrict__ bar) {
  const int tid = threadIdx.x;
  const int lane = tid & 63;
  const int w = tid >> 6;
  const int nb = gridDim.x;            // 32
  const int dir = blockIdx.x >> 4;
  const int blk = blockIdx.x & 15;
  const int wi = blk * 4 + w;          // 0..63
  const int mtile = wi & 1;
  const int npair = wi >> 1;           // 0..31
  const int c = lane & 15;
  const int q8 = (lane >> 4) * 8;
  const int arow = mtile * 16 + c;
  const int n0 = npair * 32 + c;
  const int n1 = n0 + 16;
  const unsigned short* w0p = Whh + (size_t)dir * 1024 * 1024 + (size_t)n0 * 1024 + q8;
  const unsigned short* w1p = w0p + 16 * 1024;
  unsigned short* hb = hbuf + (size_t)dir * 2 * 32 * 1024;
  const float* Gd = G + (size_t)dir * 4096 * 1024;

  for (int s = 0; s < 128; ++s) {
    const int t = dir ? (127 - s) : s;
    const unsigned short* hs = (s == 0) ? h0 : (hb + ((s - 1) & 1) * 32 * 1024);
    const unsigned short* ap = hs + (size_t)arow * 1024 + q8;
    f32x4 acc0 = {0.f, 0.f, 0.f, 0.f}, acc1 = {0.f, 0.f, 0.f, 0.f};
#pragma unroll 8
    for (int kk = 0; kk < 1024; kk += 32) {
      bf16x8 a  = ldh16(ap + kk);                 // bypass load: fresh from LLC
      bf16x8 b0 = *(const bf16x8*)(w0p + kk);     // Whh: stays L2-hot all 128 steps
      bf16x8 b1 = *(const bf16x8*)(w1p + kk);
      acc0 = __builtin_amdgcn_mfma_f32_16x16x32_bf16(a, b0, acc0, 0, 0, 0);
      acc1 = __builtin_amdgcn_mfma_f32_16x16x32_bf16(a, b1, acc1, 0, 0, 0);
    }
    unsigned short* hw = hb + (s & 1) * 32 * 1024;
    const float* Gt = Gd + (size_t)t * 32 * 1024;
    unsigned short* xo = xout + (size_t)t * 32 * 2048 + dir * 1024;
#pragma unroll
    for (int r = 0; r < 4; ++r) {
      int b = mtile * 16 + (lane >> 4) * 4 + r;
      float v0 = fmaxf(acc0[r] + Gt[b * 1024 + n0], 0.f);
      float v1 = fmaxf(acc1[r] + Gt[b * 1024 + n1], 0.f);
      unsigned short u0 = f2bf(v0), u1 = f2bf(v1);
      sth(&hw[b * 1024 + n0], u0);                // write-through to LLC
      sth(&hw[b * 1024 + n1], u1);
      xo[(size_t)b * 2048 + n0] = u0;             // ordinary store; consumed next kernel
      xo[(size_t)b * 2048 + n1] = u1;
    }
    if (s != 127) gbar(bar, nb, s + 1);
  }
}

// ---------------------------------------------------------------- LN(E=512)+relu -> bf16
__global__ __launch_bounds__(256) void ln_relu(
    const float* __restrict__ z, const float* __restrict__ g,
    const float* __restrict__ be, unsigned short* __restrict__ o) {
  const int row = blockIdx.x, tid = threadIdx.x;
  const float* zr = z + (size_t)row * 512;
  float a = zr[tid], b = zr[tid + 256];
  float s1 = a + b, s2 = a * a + b * b;
  s1 = wred2(s1); s2 = wred2(s2);
  __shared__ float r1[4], r2[4];
  if ((tid & 63) == 0) { r1[tid >> 6] = s1; r2[tid >> 6] = s2; }
  __syncthreads();
  float t1 = r1[0] + r1[1] + r1[2] + r1[3];
  float t2 = r2[0] + r2[1] + r2[2] + r2[3];
  float mu = t1 * (1.f / 512.f);
  float var = t2 * (1.f / 512.f) - mu * mu;
  float rs = rsqrtf(var + 1e-5f);
  float v0 = fmaxf((a - mu) * rs * g[tid] + be[tid], 0.f);
  float v1 = fmaxf((b - mu) * rs * g[tid + 256] + be[tid + 256], 0.f);
  o[(size_t)row * 512 + tid] = f2bf(v0);
  o[(size_t)row * 512 + tid + 256] = f2bf(v1);
}

// ---------------------------------------------------------------- launch
extern "C" void kernel_launch(void* const* d_in, const int* in_sizes, int n_in,
                              void* d_out, int out_size, void* d_ws, size_t ws_size,
                              hipStream_t stream) {
  const float* x    = (const float*)d_in[0];
  const float* Wexp = (const float*)d_in[1];
  const float* bexp = (const float*)d_in[2];
  const float* g1   = (const float*)d_in[3];
  const float* be1  = (const float*)d_in[4];
  const float* pos  = (const float*)d_in[5];
  const float* Wih0 = (const float*)d_in[6];
  const float* Whh0 = (const float*)d_in[7];
  const float* bih0 = (const float*)d_in[8];
  const float* bhh0 = (const float*)d_in[9];
  const float* Wih1 = (const float*)d_in[10];
  const float* Whh1 = (const float*)d_in[11];
  const float* bih1 = (const float*)d_in[12];
  const float* bhh1 = (const float*)d_in[13];
  const float* Wp1  = (const float*)d_in[14];
  const float* bp1  = (const float*)d_in[15];
  const float* g2   = (const float*)d_in[16];
  const float* be2  = (const float*)d_in[17];
  const float* Wp2  = (const float*)d_in[18];
  const float* bp2  = (const float*)d_in[19];
  float* out = (float*)d_out;

  char* ws = (char*)d_ws;
  size_t off = 0;
  auto alloc = [&](size_t bytes) -> void* {
    void* p = ws + off; off += (bytes + 255) & ~(size_t)255; return p;
  };
  unsigned short* W0b   = (unsigned short*)alloc(2048ull * 1024 * 2);
  unsigned short* Whh0b = (unsigned short*)alloc(2ull * 1024 * 1024 * 2);
  unsigned short* W1b   = (unsigned short*)alloc(2048ull * 2048 * 2);
  unsigned short* Whh1b = (unsigned short*)alloc(2ull * 1024 * 1024 * 2);
  unsigned short* Wp1b  = (unsigned short*)alloc(512ull * 2048 * 2);
  unsigned short* Wp2b  = (unsigned short*)alloc(32000ull * 512 * 2);
  unsigned short* xs    = (unsigned short*)alloc(4096ull * 1024 * 2);
  unsigned short* x1    = (unsigned short*)alloc(4096ull * 2048 * 2);
  unsigned short* oseq  = (unsigned short*)alloc(4096ull * 2048 * 2);
  float* G              = (float*)alloc(2ull * 4096 * 1024 * 4);   // reused by both layers
  float* proj           = (float*)alloc(4096ull * 512 * 4);
  unsigned short* hproj = (unsigned short*)alloc(4096ull * 512 * 2);
  float* expanded       = (float*)alloc(32ull * 1024 * 4);
  unsigned short* h0b   = (unsigned short*)alloc(32ull * 1024 * 2);
  unsigned short* hbuf  = (unsigned short*)alloc(2ull * 2 * 32 * 1024 * 2);
  int* bars             = (int*)alloc(256);

  auto cv = [&](const float* s, unsigned short* d, int n) {
    int n4 = n >> 2;
    f2bf4<<<(n4 + 255) / 256, 256, 0, stream>>>(s, d, n4);
  };
  cv(Wih0, W0b, 2 * 1024 * 1024);
  cv(Whh0, Whh0b, 2 * 1024 * 1024);
  cv(Wih1, W1b, 2 * 1024 * 2048);
  cv(Whh1, Whh1b, 2 * 1024 * 1024);
  cv(Wp1, Wp1b, 512 * 2048);
  cv(Wp2, Wp2b, 32000 * 512);

  expand_k<<<32, 256, 0, stream>>>(x, Wexp, bexp, g1, be1, expanded, h0b);
  build_xs_k<<<4096, 256, 0, stream>>>(expanded, pos, xs, bars);

  // layer 0
  gemm_bt<0><<<dim3(32, 16), 256, 0, stream>>>(xs, W0b, 4096, 2048, 1024, bih0, bhh0, G);
  rnn_layer<<<32, 256, 0, stream>>>(h0b, Whh0b, G, x1, hbuf, bars + 0);
  // layer 1
  gemm_bt<0><<<dim3(32, 16), 256, 0, stream>>>(x1, W1b, 4096, 2048, 2048, bih1, bhh1, G);
  rnn_layer<<<32, 256, 0, stream>>>(h0b, Whh1b, G, oseq, hbuf, bars + 32);
  // projection head
  gemm_bt<1><<<dim3(32, 4), 256, 0, stream>>>(oseq, Wp1b, 4096, 512, 2048, bp1, nullptr, proj);
  ln_relu<<<4096, 256, 0, stream>>>(proj, g2, be2, hproj);
  gemm_bt<2><<<dim3(32, 250), 256, 0, stream>>>(hproj, Wp2b, 4096, 32000, 512, bp2, nullptr, out);
}

// Round 2
// 3416.343 us; speedup vs baseline: 1.6329x; 1.6329x over previous
//
#include <hip/hip_runtime.h>

typedef __bf16 bf16x8 __attribute__((ext_vector_type(8)));
typedef float f32x4 __attribute__((ext_vector_type(4)));

__device__ __forceinline__ unsigned short f2bf(float f) {
  union { float f; unsigned u; } v; v.f = f;
  unsigned r = v.u + 0x7FFFu + ((v.u >> 16) & 1u);
  return (unsigned short)(r >> 16);
}

__device__ __forceinline__ float wred2(float v) {
#pragma unroll
  for (int o = 32; o > 0; o >>= 1) v += __shfl_down(v, o);
  return v;
}

// ---------------------------------------------------------------- convert
__global__ __launch_bounds__(256) void f2bf4(const float* __restrict__ s,
                                             unsigned short* __restrict__ d, int n4) {
  int i = blockIdx.x * 256 + threadIdx.x;
  if (i >= n4) return;
  float4 v = ((const float4*)s)[i];
  ushort4 o = make_ushort4(f2bf(v.x), f2bf(v.y), f2bf(v.z), f2bf(v.w));
  ((ushort4*)d)[i] = o;
}

// ---------------------------------------------------------------- expand: z = x@W^T+b, LN, relu
__global__ __launch_bounds__(256) void expand_k(
    const float* __restrict__ x, const float* __restrict__ Wexp,
    const float* __restrict__ bexp, const float* __restrict__ g1,
    const float* __restrict__ be1,
    float* __restrict__ expanded, unsigned short* __restrict__ h0b) {
  const int b = blockIdx.x, tid = threadIdx.x;
  __shared__ float4 xsh[128];
  __shared__ float r1[4], r2[4];
  if (tid < 128) xsh[tid] = ((const float4*)(x + b * 512))[tid];
  __syncthreads();
  float za[4];
  float s1 = 0.f, s2 = 0.f;
#pragma unroll
  for (int i = 0; i < 4; ++i) {
    int j = tid + i * 256;
    const float4* wr = (const float4*)(Wexp + (size_t)j * 512);
    float acc = bexp[j];
    for (int k = 0; k < 128; ++k) {
      float4 xv = xsh[k], wv = wr[k];
      acc += xv.x * wv.x + xv.y * wv.y + xv.z * wv.z + xv.w * wv.w;
    }
    za[i] = acc; s1 += acc; s2 += acc * acc;
  }
  s1 = wred2(s1); s2 = wred2(s2);
  if ((tid & 63) == 0) { r1[tid >> 6] = s1; r2[tid >> 6] = s2; }
  __syncthreads();
  float t1 = r1[0] + r1[1] + r1[2] + r1[3];
  float t2 = r2[0] + r2[1] + r2[2] + r2[3];
  float mu = t1 * (1.f / 1024.f);
  float var = t2 * (1.f / 1024.f) - mu * mu;
  float rs = rsqrtf(var + 1e-5f);
#pragma unroll
  for (int i = 0; i < 4; ++i) {
    int j = tid + i * 256;
    float v = fmaxf((za[i] - mu) * rs * g1[j] + be1[j], 0.f);
    expanded[(size_t)b * 1024 + j] = v;
    h0b[(size_t)b * 1024 + j] = f2bf(v);
  }
}

// ---------------------------------------------------------------- xs[t*32+b][k] = bf16(expanded[b][k]+pos[t][k]); zero barriers
__global__ __launch_bounds__(256) void build_xs_k(
    const float* __restrict__ expanded, const float* __restrict__ pos,
    unsigned short* __restrict__ xs, int* __restrict__ bars) {
  int i = blockIdx.x * 256 + threadIdx.x;
  if (blockIdx.x == 0 && threadIdx.x < 64) bars[threadIdx.x] = 0;
  int e = i << 2;
  int row = e >> 10, k = e & 1023;
  int tt = row >> 5, bb = row & 31;
  float4 ev = *(const float4*)(expanded + (size_t)bb * 1024 + k);
  float4 pv = *(const float4*)(pos + (size_t)tt * 1024 + k);
  ushort4 o = make_ushort4(f2bf(ev.x + pv.x), f2bf(ev.y + pv.y),
                           f2bf(ev.z + pv.z), f2bf(ev.w + pv.w));
  *(ushort4*)(xs + (size_t)row * 1024 + k) = o;
}

// ---------------------------------------------------------------- bf16 MFMA GEMM: C = A @ W^T (+epilogue)
// A: [M,K] bf16 rowmajor, W: [N,K] bf16 rowmajor. M%128==0, N%128==0, K%64==0.
#define BM 128
#define BN 128
#define BKK 64
#define LDKP 72   // +8 pad: rows shift 4 banks -> uniform 2 lanes/bank on ds_read_b128

template<int EPI>
__global__ __launch_bounds__(256) void gemm_bt(
    const unsigned short* __restrict__ A, const unsigned short* __restrict__ W,
    int M, int N, int K,
    const float* __restrict__ bias0, const float* __restrict__ bias1,
    float* __restrict__ out) {
  __shared__ __align__(16) unsigned short As[BM * LDKP];
  __shared__ __align__(16) unsigned short Bs[BN * LDKP];
  const int tid = threadIdx.x;
  const int lane = tid & 63;
  const int w = tid >> 6;
  const int wm = (w & 1) * 64;
  const int wn = (w >> 1) * 64;
  const int m0 = blockIdx.x * BM;
  const int n0 = blockIdx.y * BN;
  const int srow = tid >> 3;
  const int scol = (tid & 7) * 8;
  const int c = lane & 15;
  const int q8 = (lane >> 4) * 8;
  f32x4 acc[4][4] = {};
  for (int k0 = 0; k0 < K; k0 += BKK) {
#pragma unroll
    for (int p = 0; p < 4; ++p) {
      int r = p * 32 + srow;
      *(uint4*)&As[r * LDKP + scol] = *(const uint4*)&A[(size_t)(m0 + r) * K + k0 + scol];
      *(uint4*)&Bs[r * LDKP + scol] = *(const uint4*)&W[(size_t)(n0 + r) * K + k0 + scol];
    }
    __syncthreads();
#pragma unroll
    for (int kk = 0; kk < BKK; kk += 32) {
      bf16x8 af[4], bb[4];
#pragma unroll
      for (int i = 0; i < 4; ++i)
        af[i] = *(const bf16x8*)&As[(wm + i * 16 + c) * LDKP + kk + q8];
#pragma unroll
      for (int j = 0; j < 4; ++j)
        bb[j] = *(const bf16x8*)&Bs[(wn + j * 16 + c) * LDKP + kk + q8];
#pragma unroll
      for (int i = 0; i < 4; ++i)
#pragma unroll
        for (int j = 0; j < 4; ++j)
          acc[i][j] = __builtin_amdgcn_mfma_f32_16x16x32_bf16(af[i], bb[j], acc[i][j], 0, 0, 0);
    }
    __syncthreads();
  }
  const int q = lane >> 4;
#pragma unroll
  for (int i = 0; i < 4; ++i) {
#pragma unroll
    for (int j = 0; j < 4; ++j) {
#pragma unroll
      for (int r = 0; r < 4; ++r) {
        int m = m0 + wm + i * 16 + q * 4 + r;
        int n = n0 + wn + j * 16 + c;
        float v = acc[i][j][r];
        if (EPI == 0) {            // G epilogue: +bih+bhh, [dir][m][j] layout
          v += bias0[n] + bias1[n];
          int dir = n >> 10, jj = n & 1023;
          out[(size_t)dir * M * 1024 + (size_t)m * 1024 + jj] = v;
        } else if (EPI == 1) {     // plain [M,N] + bias
          v += bias0[n];
          out[(size_t)m * N + n] = v;
        } else {                   // head: row m = t*32+b -> out[b][t][n], +bp2
          v += bias0[n];
          int b = m & 31, t = m >> 5;
          out[(size_t)(b * 128 + t) * 32000 + n] = v;
        }
      }
    }
  }
}

// ---------------------------------------------------------------- cache-bypass h exchange
// h is written with agent-scope write-through stores (land at LLC, never dirty in
// per-XCD L2) and read with agent-scope bypass loads (never cached in L1/L2).
// => no L2 writeback/invalidate anywhere in the 128-step loop.
__device__ __forceinline__ bf16x8 ldh16(const unsigned short* p) {
  union { unsigned long long q[2]; bf16x8 v; } u;
  unsigned long long* pq = (unsigned long long*)p;
  u.q[0] = __hip_atomic_load(pq,     __ATOMIC_RELAXED, __HIP_MEMORY_SCOPE_AGENT);
  u.q[1] = __hip_atomic_load(pq + 1, __ATOMIC_RELAXED, __HIP_MEMORY_SCOPE_AGENT);
  return u.v;
}

__device__ __forceinline__ void sth(unsigned short* p, unsigned short v) {
  __hip_atomic_store(p, v, __ATOMIC_RELAXED, __HIP_MEMORY_SCOPE_AGENT);
}

// ---------------------------------------------------------------- grid barrier (monotonic counter, fence-free)
__device__ __forceinline__ void gbar(int* bar, int nblocks, int phase) {
  asm volatile("s_waitcnt vmcnt(0)" ::: "memory");  // every wave drains its own stores
  __syncthreads();
  if (threadIdx.x == 0) {
    __hip_atomic_fetch_add(bar, 1, __ATOMIC_RELAXED, __HIP_MEMORY_SCOPE_AGENT);
    const int target = nblocks * phase;
    while (__hip_atomic_load(bar, __ATOMIC_RELAXED, __HIP_MEMORY_SCOPE_AGENT) < target)
      __builtin_amdgcn_s_sleep(2);
  }
  __syncthreads();
}

// ---------------------------------------------------------------- persistent bidirectional RNN layer
// h_new = relu(G[dir][t] + h @ Whh[dir]^T); xout[t][b][dir*1024+j] = h_new
// 32 blocks x 256 thr; wave = (mtile in 0..1) x (npair in 0..31 -> 2 n-tiles)
// Whh fragments live in REGISTERS for all 128 steps (64 x bf16x8 = 256 VGPRs):
// per-step memory traffic is only h (batched independent LLC loads) + G + stores.
__global__ __launch_bounds__(256, 1) void rnn_layer(
    const unsigned short* __restrict__ h0,     // [32][1024] bf16
    const unsigned short* __restrict__ Whh,    // [2][1024][1024] bf16
    const float* __restrict__ G,               // [2][4096][1024] fp32, row=t*32+b
    unsigned short* __restrict__ xout,         // [4096][2048] bf16, row=t*32+b
    unsigned short* __restrict__ hbuf,         // [2][2][32][1024] bf16 ping-pong
    int* __restrict__ bar) {
  const int tid = threadIdx.x;
  const int lane = tid & 63;
  const int w = tid >> 6;
  const int nb = gridDim.x;            // 32
  const int dir = blockIdx.x >> 4;
  const int blk = blockIdx.x & 15;
  const int wi = blk * 4 + w;          // 0..63
  const int mtile = wi & 1;
  const int npair = wi >> 1;           // 0..31
  const int c = lane & 15;
  const int q8 = (lane >> 4) * 8;
  const int arow = mtile * 16 + c;
  const int n0 = npair * 32 + c;
  const int n1 = n0 + 16;
  const unsigned short* w0p = Whh + (size_t)dir * 1024 * 1024 + (size_t)n0 * 1024 + q8;
  const unsigned short* w1p = w0p + 16 * 1024;
  unsigned short* hb = hbuf + (size_t)dir * 2 * 32 * 1024;
  const float* Gd = G + (size_t)dir * 4096 * 1024;
  const int brow = mtile * 16 + (lane >> 4) * 4;   // epilogue batch-row base

  // ---- Whh resident in registers, reused by all 128 steps
  bf16x8 wr0[32], wr1[32];
#pragma unroll
  for (int i = 0; i < 32; ++i) {
    wr0[i] = *(const bf16x8*)(w0p + i * 32);
    wr1[i] = *(const bf16x8*)(w1p + i * 32);
  }

  for (int s = 0; s < 128; ++s) {
    const int t = dir ? (127 - s) : s;
    const unsigned short* hs = (s == 0) ? h0 : (hb + ((s - 1) & 1) * 32 * 1024);
    const unsigned short* ap = hs + (size_t)arow * 1024 + q8;
    const float* Gt = Gd + (size_t)t * 32 * 1024;

    // ---- issue ALL independent loads for this step up front
    bf16x8 areg[32];
#pragma unroll
    for (int i = 0; i < 32; ++i) areg[i] = ldh16(ap + i * 32);
    float gg0[4], gg1[4];
#pragma unroll
    for (int r = 0; r < 4; ++r) {
      gg0[r] = Gt[(size_t)(brow + r) * 1024 + n0];
      gg1[r] = Gt[(size_t)(brow + r) * 1024 + n1];
    }

    // ---- pure-register MFMA sweep
    f32x4 acc0 = {0.f, 0.f, 0.f, 0.f}, acc1 = {0.f, 0.f, 0.f, 0.f};
#pragma unroll
    for (int i = 0; i < 32; ++i) {
      acc0 = __builtin_amdgcn_mfma_f32_16x16x32_bf16(areg[i], wr0[i], acc0, 0, 0, 0);
      acc1 = __builtin_amdgcn_mfma_f32_16x16x32_bf16(areg[i], wr1[i], acc1, 0, 0, 0);
    }

    unsigned short* hw = hb + (s & 1) * 32 * 1024;
    unsigned short* xo = xout + (size_t)t * 32 * 2048 + dir * 1024;
#pragma unroll
    for (int r = 0; r < 4; ++r) {
      int b = brow + r;
      float v0 = fmaxf(acc0[r] + gg0[r], 0.f);
      float v1 = fmaxf(acc1[r] + gg1[r], 0.f);
      unsigned short u0 = f2bf(v0), u1 = f2bf(v1);
      sth(&hw[b * 1024 + n0], u0);                // write-through to LLC
      sth(&hw[b * 1024 + n1], u1);
      xo[(size_t)b * 2048 + n0] = u0;             // ordinary store; consumed next kernel
      xo[(size_t)b * 2048 + n1] = u1;
    }
    if (s != 127) gbar(bar, nb, s + 1);
  }
}

// ---------------------------------------------------------------- LN(E=512)+relu -> bf16
__global__ __launch_bounds__(256) void ln_relu(
    const float* __restrict__ z, const float* __restrict__ g,
    const float* __restrict__ be, unsigned short* __restrict__ o) {
  const int row = blockIdx.x, tid = threadIdx.x;
  const float* zr = z + (size_t)row * 512;
  float a = zr[tid], b = zr[tid + 256];
  float s1 = a + b, s2 = a * a + b * b;
  s1 = wred2(s1); s2 = wred2(s2);
  __shared__ float r1[4], r2[4];
  if ((tid & 63) == 0) { r1[tid >> 6] = s1; r2[tid >> 6] = s2; }
  __syncthreads();
  float t1 = r1[0] + r1[1] + r1[2] + r1[3];
  float t2 = r2[0] + r2[1] + r2[2] + r2[3];
  float mu = t1 * (1.f / 512.f);
  float var = t2 * (1.f / 512.f) - mu * mu;
  float rs = rsqrtf(var + 1e-5f);
  float v0 = fmaxf((a - mu) * rs * g[tid] + be[tid], 0.f);
  float v1 = fmaxf((b - mu) * rs * g[tid + 256] + be[tid + 256], 0.f);
  o[(size_t)row * 512 + tid] = f2bf(v0);
  o[(size_t)row * 512 + tid + 256] = f2bf(v1);
}

// ---------------------------------------------------------------- launch
extern "C" void kernel_launch(void* const* d_in, const int* in_sizes, int n_in,
                              void* d_out, int out_size, void* d_ws, size_t ws_size,
                              hipStream_t stream) {
  const float* x    = (const float*)d_in[0];
  const float* Wexp = (const float*)d_in[1];
  const float* bexp = (const float*)d_in[2];
  const float* g1   = (const float*)d_in[3];
  const float* be1  = (const float*)d_in[4];
  const float* pos  = (const float*)d_in[5];
  const float* Wih0 = (const float*)d_in[6];
  const float* Whh0 = (const float*)d_in[7];
  const float* bih0 = (const float*)d_in[8];
  const float* bhh0 = (const float*)d_in[9];
  const float* Wih1 = (const float*)d_in[10];
  const float* Whh1 = (const float*)d_in[11];
  const float* bih1 = (const float*)d_in[12];
  const float* bhh1 = (const float*)d_in[13];
  const float* Wp1  = (const float*)d_in[14];
  const float* bp1  = (const float*)d_in[15];
  const float* g2   = (const float*)d_in[16];
  const float* be2  = (const float*)d_in[17];
  const float* Wp2  = (const float*)d_in[18];
  const float* bp2  = (const float*)d_in[19];
  float* out = (float*)d_out;

  char* ws = (char*)d_ws;
  size_t off = 0;
  auto alloc = [&](size_t bytes) -> void* {
    void* p = ws + off; off += (bytes + 255) & ~(size_t)255; return p;
  };
  unsigned short* W0b   = (unsigned short*)alloc(2048ull * 1024 * 2);
  unsigned short* Whh0b = (unsigned short*)alloc(2ull * 1024 * 1024 * 2);
  unsigned short* W1b   = (unsigned short*)alloc(2048ull * 2048 * 2);
  unsigned short* Whh1b = (unsigned short*)alloc(2ull * 1024 * 1024 * 2);
  unsigned short* Wp1b  = (unsigned short*)alloc(512ull * 2048 * 2);
  unsigned short* Wp2b  = (unsigned short*)alloc(32000ull * 512 * 2);
  unsigned short* xs    = (unsigned short*)alloc(4096ull * 1024 * 2);
  unsigned short* x1    = (unsigned short*)alloc(4096ull * 2048 * 2);
  unsigned short* oseq  = (unsigned short*)alloc(4096ull * 2048 * 2);
  float* G              = (float*)alloc(2ull * 4096 * 1024 * 4);   // reused by both layers
  float* proj           = (float*)alloc(4096ull * 512 * 4);
  unsigned short* hproj = (unsigned short*)alloc(4096ull * 512 * 2);
  float* expanded       = (float*)alloc(32ull * 1024 * 4);
  unsigned short* h0b   = (unsigned short*)alloc(32ull * 1024 * 2);
  unsigned short* hbuf  = (unsigned short*)alloc(2ull * 2 * 32 * 1024 * 2);
  int* bars             = (int*)alloc(256);

  auto cv = [&](const float* s, unsigned short* d, int n) {
    int n4 = n >> 2;
    f2bf4<<<(n4 + 255) / 256, 256, 0, stream>>>(s, d, n4);
  };
  cv(Wih0, W0b, 2 * 1024 * 1024);
  cv(Whh0, Whh0b, 2 * 1024 * 1024);
  cv(Wih1, W1b, 2 * 1024 * 2048);
  cv(Whh1, Whh1b, 2 * 1024 * 1024);
  cv(Wp1, Wp1b, 512 * 2048);
  cv(Wp2, Wp2b, 32000 * 512);

  expand_k<<<32, 256, 0, stream>>>(x, Wexp, bexp, g1, be1, expanded, h0b);
  build_xs_k<<<4096, 256, 0, stream>>>(expanded, pos, xs, bars);

  // layer 0
  gemm_bt<0><<<dim3(32, 16), 256, 0, stream>>>(xs, W0b, 4096, 2048, 1024, bih0, bhh0, G);
  rnn_layer<<<32, 256, 0, stream>>>(h0b, Whh0b, G, x1, hbuf, bars + 0);
  // layer 1
  gemm_bt<0><<<dim3(32, 16), 256, 0, stream>>>(x1, W1b, 4096, 2048, 2048, bih1, bhh1, G);
  rnn_layer<<<32, 256, 0, stream>>>(h0b, Whh1b, G, oseq, hbuf, bars + 32);
  // projection head
  gemm_bt<1><<<dim3(32, 4), 256, 0, stream>>>(oseq, Wp1b, 4096, 512, 2048, bp1, nullptr, proj);
  ln_relu<<<4096, 256, 0, stream>>>(proj, g2, be2, hproj);
  gemm_bt<2><<<dim3(32, 250), 256, 0, stream>>>(hproj, Wp2b, 4096, 32000, 512, bp2, nullptr, out);
}

// Round 3
// 2425.795 us; speedup vs baseline: 2.2997x; 1.4083x over previous
//
#include <hip/hip_runtime.h>

typedef __bf16 bf16x8 __attribute__((ext_vector_type(8)));
typedef float f32x4 __attribute__((ext_vector_type(4)));

__device__ __forceinline__ unsigned short f2bf(float f) {
  union { float f; unsigned u; } v; v.f = f;
  unsigned r = v.u + 0x7FFFu + ((v.u >> 16) & 1u);
  return (unsigned short)(r >> 16);
}

__device__ __forceinline__ float wred2(float v) {
#pragma unroll
  for (int o = 32; o > 0; o >>= 1) v += __shfl_down(v, o);
  return v;
}

// ---------------------------------------------------------------- convert
__global__ __launch_bounds__(256) void f2bf4(const float* __restrict__ s,
                                             unsigned short* __restrict__ d, int n4) {
  int i = blockIdx.x * 256 + threadIdx.x;
  if (i >= n4) return;
  float4 v = ((const float4*)s)[i];
  ushort4 o = make_ushort4(f2bf(v.x), f2bf(v.y), f2bf(v.z), f2bf(v.w));
  ((ushort4*)d)[i] = o;
}

// ---------------------------------------------------------------- expand: z = x@W^T+b, LN, relu
__global__ __launch_bounds__(256) void expand_k(
    const float* __restrict__ x, const float* __restrict__ Wexp,
    const float* __restrict__ bexp, const float* __restrict__ g1,
    const float* __restrict__ be1,
    float* __restrict__ expanded, unsigned short* __restrict__ h0b) {
  const int b = blockIdx.x, tid = threadIdx.x;
  __shared__ float4 xsh[128];
  __shared__ float r1[4], r2[4];
  if (tid < 128) xsh[tid] = ((const float4*)(x + b * 512))[tid];
  __syncthreads();
  float za[4];
  float s1 = 0.f, s2 = 0.f;
#pragma unroll
  for (int i = 0; i < 4; ++i) {
    int j = tid + i * 256;
    const float4* wr = (const float4*)(Wexp + (size_t)j * 512);
    float acc = bexp[j];
    for (int k = 0; k < 128; ++k) {
      float4 xv = xsh[k], wv = wr[k];
      acc += xv.x * wv.x + xv.y * wv.y + xv.z * wv.z + xv.w * wv.w;
    }
    za[i] = acc; s1 += acc; s2 += acc * acc;
  }
  s1 = wred2(s1); s2 = wred2(s2);
  if ((tid & 63) == 0) { r1[tid >> 6] = s1; r2[tid >> 6] = s2; }
  __syncthreads();
  float t1 = r1[0] + r1[1] + r1[2] + r1[3];
  float t2 = r2[0] + r2[1] + r2[2] + r2[3];
  float mu = t1 * (1.f / 1024.f);
  float var = t2 * (1.f / 1024.f) - mu * mu;
  float rs = rsqrtf(var + 1e-5f);
#pragma unroll
  for (int i = 0; i < 4; ++i) {
    int j = tid + i * 256;
    float v = fmaxf((za[i] - mu) * rs * g1[j] + be1[j], 0.f);
    expanded[(size_t)b * 1024 + j] = v;
    h0b[(size_t)b * 1024 + j] = f2bf(v);
  }
}

// ---------------------------------------------------------------- xs[t*32+b][k] = bf16(expanded[b][k]+pos[t][k]); zero barriers
__global__ __launch_bounds__(256) void build_xs_k(
    const float* __restrict__ expanded, const float* __restrict__ pos,
    unsigned short* __restrict__ xs, int* __restrict__ bars) {
  int i = blockIdx.x * 256 + threadIdx.x;
  if (blockIdx.x == 0 && threadIdx.x < 64) bars[threadIdx.x] = 0;
  int e = i << 2;
  int row = e >> 10, k = e & 1023;
  int tt = row >> 5, bb = row & 31;
  float4 ev = *(const float4*)(expanded + (size_t)bb * 1024 + k);
  float4 pv = *(const float4*)(pos + (size_t)tt * 1024 + k);
  ushort4 o = make_ushort4(f2bf(ev.x + pv.x), f2bf(ev.y + pv.y),
                           f2bf(ev.z + pv.z), f2bf(ev.w + pv.w));
  *(ushort4*)(xs + (size_t)row * 1024 + k) = o;
}

// ---------------------------------------------------------------- bf16 MFMA GEMM: C = A @ W^T (+epilogue)
// A: [M,K] bf16 rowmajor, W: [N,K] bf16 rowmajor. M%128==0, N%128==0, K%64==0.
#define BM 128
#define BN 128
#define BKK 64
#define LDKP 72   // +8 pad: rows shift 4 banks -> uniform 2 lanes/bank on ds_read_b128

template<int EPI>
__global__ __launch_bounds__(256) void gemm_bt(
    const unsigned short* __restrict__ A, const unsigned short* __restrict__ W,
    int M, int N, int K,
    const float* __restrict__ bias0, const float* __restrict__ bias1,
    float* __restrict__ out) {
  __shared__ __align__(16) unsigned short As[BM * LDKP];
  __shared__ __align__(16) unsigned short Bs[BN * LDKP];
  const int tid = threadIdx.x;
  const int lane = tid & 63;
  const int w = tid >> 6;
  const int wm = (w & 1) * 64;
  const int wn = (w >> 1) * 64;
  const int m0 = blockIdx.x * BM;
  const int n0 = blockIdx.y * BN;
  const int srow = tid >> 3;
  const int scol = (tid & 7) * 8;
  const int c = lane & 15;
  const int q8 = (lane >> 4) * 8;
  f32x4 acc[4][4] = {};
  for (int k0 = 0; k0 < K; k0 += BKK) {
#pragma unroll
    for (int p = 0; p < 4; ++p) {
      int r = p * 32 + srow;
      *(uint4*)&As[r * LDKP + scol] = *(const uint4*)&A[(size_t)(m0 + r) * K + k0 + scol];
      *(uint4*)&Bs[r * LDKP + scol] = *(const uint4*)&W[(size_t)(n0 + r) * K + k0 + scol];
    }
    __syncthreads();
#pragma unroll
    for (int kk = 0; kk < BKK; kk += 32) {
      bf16x8 af[4], bb[4];
#pragma unroll
      for (int i = 0; i < 4; ++i)
        af[i] = *(const bf16x8*)&As[(wm + i * 16 + c) * LDKP + kk + q8];
#pragma unroll
      for (int j = 0; j < 4; ++j)
        bb[j] = *(const bf16x8*)&Bs[(wn + j * 16 + c) * LDKP + kk + q8];
#pragma unroll
      for (int i = 0; i < 4; ++i)
#pragma unroll
        for (int j = 0; j < 4; ++j)
          acc[i][j] = __builtin_amdgcn_mfma_f32_16x16x32_bf16(af[i], bb[j], acc[i][j], 0, 0, 0);
    }
    __syncthreads();
  }
  const int q = lane >> 4;
#pragma unroll
  for (int i = 0; i < 4; ++i) {
#pragma unroll
    for (int j = 0; j < 4; ++j) {
#pragma unroll
      for (int r = 0; r < 4; ++r) {
        int m = m0 + wm + i * 16 + q * 4 + r;
        int n = n0 + wn + j * 16 + c;
        float v = acc[i][j][r];
        if (EPI == 0) {            // G epilogue: +bih+bhh, [dir][m][j] layout
          v += bias0[n] + bias1[n];
          int dir = n >> 10, jj = n & 1023;
          out[(size_t)dir * M * 1024 + (size_t)m * 1024 + jj] = v;
        } else if (EPI == 1) {     // plain [M,N] + bias
          v += bias0[n];
          out[(size_t)m * N + n] = v;
        } else {                   // head: row m = t*32+b -> out[b][t][n], +bp2
          v += bias0[n];
          int b = m & 31, t = m >> 5;
          out[(size_t)(b * 128 + t) * 32000 + n] = v;
        }
      }
    }
  }
}

// ---------------------------------------------------------------- cache-bypass h exchange
__device__ __forceinline__ bf16x8 ldh16(const unsigned short* p) {
  union { unsigned long long q[2]; bf16x8 v; } u;
  unsigned long long* pq = (unsigned long long*)p;
  u.q[0] = __hip_atomic_load(pq,     __ATOMIC_RELAXED, __HIP_MEMORY_SCOPE_AGENT);
  u.q[1] = __hip_atomic_load(pq + 1, __ATOMIC_RELAXED, __HIP_MEMORY_SCOPE_AGENT);
  return u.v;
}

__device__ __forceinline__ void sth(unsigned short* p, unsigned short v) {
  __hip_atomic_store(p, v, __ATOMIC_RELAXED, __HIP_MEMORY_SCOPE_AGENT);
}

// ---------------------------------------------------------------- persistent bidirectional RNN layer
// h_new = relu(G[dir][t] + h @ Whh[dir]^T); xout[t][b][dir*1024+j] = h_new
// 32 blocks x 256 thr; per-DIR barrier over 16 blocks (counters 64B apart).
// Whh resident in registers. hbuf uses consumer-optimal layout
// [dir][parity][kchunk 0..31][row 0..31][32 elems] so exchange loads are
// fully contiguous 512B/wave. Per-step critical path:
//   poll -> h loads -> MFMA -> epilogue(reg G) -> h stores -> vmcnt(0) -> publish
// xout stores + next-step G prefetch are issued in the poll window (off-path).
__global__ __launch_bounds__(256, 1) void rnn_layer(
    const unsigned short* __restrict__ h0,     // [32][1024] bf16
    const unsigned short* __restrict__ Whh,    // [2][1024][1024] bf16
    const float* __restrict__ G,               // [2][4096][1024] fp32, row=t*32+b
    unsigned short* __restrict__ xout,         // [4096][2048] bf16, row=t*32+b
    unsigned short* __restrict__ hbuf,         // [2][2][32][32][32] bf16 ping-pong
    int* __restrict__ bar) {
  const int tid = threadIdx.x;
  const int lane = tid & 63;
  const int w = tid >> 6;
  const int dir = blockIdx.x >> 4;
  const int blk = blockIdx.x & 15;
  const int wi = blk * 4 + w;          // 0..63
  const int mtile = wi & 1;
  const int npair = wi >> 1;           // 0..31
  const int c = lane & 15;
  const int qg = lane >> 4;
  const int q8 = qg * 8;
  const int arow = mtile * 16 + c;
  const int n0 = npair * 32 + c;
  const int n1 = n0 + 16;
  const unsigned short* w0p = Whh + (size_t)dir * 1024 * 1024 + (size_t)n0 * 1024 + q8;
  const unsigned short* w1p = w0p + 16 * 1024;
  unsigned short* hb = hbuf + (size_t)dir * 2 * 32768;   // [par][32][32][32]
  const float* Gd = G + (size_t)dir * 4096 * 1024;
  const int brow = mtile * 16 + qg * 4;                  // epilogue batch-row base
  int* bar2 = bar + dir * 16;                            // per-dir counter, 64B apart
  const int laneelem = mtile * 512 + c * 32 + q8;        // consumer lane offset

  // ---- Whh resident in registers, reused by all 128 steps
  bf16x8 wr0[32], wr1[32];
#pragma unroll
  for (int i = 0; i < 32; ++i) {
    wr0[i] = *(const bf16x8*)(w0p + i * 32);
    wr1[i] = *(const bf16x8*)(w1p + i * 32);
  }

  // ---- G prefetch for step 0
  float gg0[4], gg1[4];
  {
    const int t0 = dir ? 127 : 0;
    const float* Gt = Gd + (size_t)t0 * 32 * 1024;
#pragma unroll
    for (int r = 0; r < 4; ++r) {
      gg0[r] = Gt[(size_t)(brow + r) * 1024 + n0];
      gg1[r] = Gt[(size_t)(brow + r) * 1024 + n1];
    }
  }

  for (int s = 0; s < 128; ++s) {
    const int t = dir ? (127 - s) : s;

    // ---- load h (batched, independent)
    bf16x8 areg[32];
    if (s == 0) {
      const unsigned short* ap = h0 + (size_t)arow * 1024 + q8;
#pragma unroll
      for (int i = 0; i < 32; ++i) areg[i] = *(const bf16x8*)(ap + i * 32);
    } else {
      const unsigned short* hbase = hb + ((s - 1) & 1) * 32768 + laneelem;
#pragma unroll
      for (int i = 0; i < 32; ++i) areg[i] = ldh16(hbase + i * 1024);
    }

    // ---- pure-register MFMA sweep, 2 chains per accumulator
    f32x4 a0a = {0.f,0.f,0.f,0.f}, a0b = {0.f,0.f,0.f,0.f};
    f32x4 a1a = {0.f,0.f,0.f,0.f}, a1b = {0.f,0.f,0.f,0.f};
#pragma unroll
    for (int i = 0; i < 32; i += 2) {
      a0a = __builtin_amdgcn_mfma_f32_16x16x32_bf16(areg[i],     wr0[i],     a0a, 0, 0, 0);
      a1a = __builtin_amdgcn_mfma_f32_16x16x32_bf16(areg[i],     wr1[i],     a1a, 0, 0, 0);
      a0b = __builtin_amdgcn_mfma_f32_16x16x32_bf16(areg[i + 1], wr0[i + 1], a0b, 0, 0, 0);
      a1b = __builtin_amdgcn_mfma_f32_16x16x32_bf16(areg[i + 1], wr1[i + 1], a1b, 0, 0, 0);
    }
    f32x4 acc0 = a0a + a0b, acc1 = a1a + a1b;

    // ---- epilogue (G already in registers) + h store (consumer layout)
    unsigned short* hw = hb + (s & 1) * 32768 + npair * 1024;
    unsigned short u0s[4], u1s[4];
#pragma unroll
    for (int r = 0; r < 4; ++r) {
      int b = brow + r;
      float v0 = fmaxf(acc0[r] + gg0[r], 0.f);
      float v1 = fmaxf(acc1[r] + gg1[r], 0.f);
      u0s[r] = f2bf(v0); u1s[r] = f2bf(v1);
      sth(&hw[b * 32 + c], u0s[r]);            // write-through to LLC
      sth(&hw[b * 32 + c + 16], u1s[r]);
    }

    if (s != 127) {
      // ---- drain h stores, publish arrival
      asm volatile("s_waitcnt vmcnt(0)" ::: "memory");
      __syncthreads();
      if (tid == 0)
        __hip_atomic_fetch_add(bar2, 1, __ATOMIC_RELAXED, __HIP_MEMORY_SCOPE_AGENT);

      // ---- off-critical-path work inside the wait window
      unsigned short* xo = xout + (size_t)t * 32 * 2048 + dir * 1024;
#pragma unroll
      for (int r = 0; r < 4; ++r) {
        int b = brow + r;
        xo[(size_t)b * 2048 + n0] = u0s[r];
        xo[(size_t)b * 2048 + n1] = u1s[r];
      }
      const int tn = dir ? (127 - (s + 1)) : (s + 1);
      const float* Gtn = Gd + (size_t)tn * 32 * 1024;
#pragma unroll
      for (int r = 0; r < 4; ++r) {
        gg0[r] = Gtn[(size_t)(brow + r) * 1024 + n0];
        gg1[r] = Gtn[(size_t)(brow + r) * 1024 + n1];
      }

      // ---- wait for all 16 blocks of this direction
      if (tid == 0) {
        const int target = 16 * (s + 1);
        while (__hip_atomic_load(bar2, __ATOMIC_RELAXED, __HIP_MEMORY_SCOPE_AGENT) < target)
          __builtin_amdgcn_s_sleep(1);
      }
      __syncthreads();
    } else {
      unsigned short* xo = xout + (size_t)t * 32 * 2048 + dir * 1024;
#pragma unroll
      for (int r = 0; r < 4; ++r) {
        int b = brow + r;
        xo[(size_t)b * 2048 + n0] = u0s[r];
        xo[(size_t)b * 2048 + n1] = u1s[r];
      }
    }
  }
}

// ---------------------------------------------------------------- LN(E=512)+relu -> bf16
__global__ __launch_bounds__(256) void ln_relu(
    const float* __restrict__ z, const float* __restrict__ g,
    const float* __restrict__ be, unsigned short* __restrict__ o) {
  const int row = blockIdx.x, tid = threadIdx.x;
  const float* zr = z + (size_t)row * 512;
  float a = zr[tid], b = zr[tid + 256];
  float s1 = a + b, s2 = a * a + b * b;
  s1 = wred2(s1); s2 = wred2(s2);
  __shared__ float r1[4], r2[4];
  if ((tid & 63) == 0) { r1[tid >> 6] = s1; r2[tid >> 6] = s2; }
  __syncthreads();
  float t1 = r1[0] + r1[1] + r1[2] + r1[3];
  float t2 = r2[0] + r2[1] + r2[2] + r2[3];
  float mu = t1 * (1.f / 512.f);
  float var = t2 * (1.f / 512.f) - mu * mu;
  float rs = rsqrtf(var + 1e-5f);
  float v0 = fmaxf((a - mu) * rs * g[tid] + be[tid], 0.f);
  float v1 = fmaxf((b - mu) * rs * g[tid + 256] + be[tid + 256], 0.f);
  o[(size_t)row * 512 + tid] = f2bf(v0);
  o[(size_t)row * 512 + tid + 256] = f2bf(v1);
}

// ---------------------------------------------------------------- launch
extern "C" void kernel_launch(void* const* d_in, const int* in_sizes, int n_in,
                              void* d_out, int out_size, void* d_ws, size_t ws_size,
                              hipStream_t stream) {
  const float* x    = (const float*)d_in[0];
  const float* Wexp = (const float*)d_in[1];
  const float* bexp = (const float*)d_in[2];
  const float* g1   = (const float*)d_in[3];
  const float* be1  = (const float*)d_in[4];
  const float* pos  = (const float*)d_in[5];
  const float* Wih0 = (const float*)d_in[6];
  const float* Whh0 = (const float*)d_in[7];
  const float* bih0 = (const float*)d_in[8];
  const float* bhh0 = (const float*)d_in[9];
  const float* Wih1 = (const float*)d_in[10];
  const float* Whh1 = (const float*)d_in[11];
  const float* bih1 = (const float*)d_in[12];
  const float* bhh1 = (const float*)d_in[13];
  const float* Wp1  = (const float*)d_in[14];
  const float* bp1  = (const float*)d_in[15];
  const float* g2   = (const float*)d_in[16];
  const float* be2  = (const float*)d_in[17];
  const float* Wp2  = (const float*)d_in[18];
  const float* bp2  = (const float*)d_in[19];
  float* out = (float*)d_out;

  char* ws = (char*)d_ws;
  size_t off = 0;
  auto alloc = [&](size_t bytes) -> void* {
    void* p = ws + off; off += (bytes + 255) & ~(size_t)255; return p;
  };
  unsigned short* W0b   = (unsigned short*)alloc(2048ull * 1024 * 2);
  unsigned short* Whh0b = (unsigned short*)alloc(2ull * 1024 * 1024 * 2);
  unsigned short* W1b   = (unsigned short*)alloc(2048ull * 2048 * 2);
  unsigned short* Whh1b = (unsigned short*)alloc(2ull * 1024 * 1024 * 2);
  unsigned short* Wp1b  = (unsigned short*)alloc(512ull * 2048 * 2);
  unsigned short* Wp2b  = (unsigned short*)alloc(32000ull * 512 * 2);
  unsigned short* xs    = (unsigned short*)alloc(4096ull * 1024 * 2);
  unsigned short* x1    = (unsigned short*)alloc(4096ull * 2048 * 2);
  unsigned short* oseq  = (unsigned short*)alloc(4096ull * 2048 * 2);
  float* G              = (float*)alloc(2ull * 4096 * 1024 * 4);   // reused by both layers
  float* proj           = (float*)alloc(4096ull * 512 * 4);
  unsigned short* hproj = (unsigned short*)alloc(4096ull * 512 * 2);
  float* expanded       = (float*)alloc(32ull * 1024 * 4);
  unsigned short* h0b   = (unsigned short*)alloc(32ull * 1024 * 2);
  unsigned short* hbuf  = (unsigned short*)alloc(2ull * 2 * 32 * 1024 * 2);
  int* bars             = (int*)alloc(256);

  auto cv = [&](const float* s, unsigned short* d, int n) {
    int n4 = n >> 2;
    f2bf4<<<(n4 + 255) / 256, 256, 0, stream>>>(s, d, n4);
  };
  cv(Wih0, W0b, 2 * 1024 * 1024);
  cv(Whh0, Whh0b, 2 * 1024 * 1024);
  cv(Wih1, W1b, 2 * 1024 * 2048);
  cv(Whh1, Whh1b, 2 * 1024 * 1024);
  cv(Wp1, Wp1b, 512 * 2048);
  cv(Wp2, Wp2b, 32000 * 512);

  expand_k<<<32, 256, 0, stream>>>(x, Wexp, bexp, g1, be1, expanded, h0b);
  build_xs_k<<<4096, 256, 0, stream>>>(expanded, pos, xs, bars);

  // layer 0
  gemm_bt<0><<<dim3(32, 16), 256, 0, stream>>>(xs, W0b, 4096, 2048, 1024, bih0, bhh0, G);
  rnn_layer<<<32, 256, 0, stream>>>(h0b, Whh0b, G, x1, hbuf, bars + 0);
  // layer 1
  gemm_bt<0><<<dim3(32, 16), 256, 0, stream>>>(x1, W1b, 4096, 2048, 2048, bih1, bhh1, G);
  rnn_layer<<<32, 256, 0, stream>>>(h0b, Whh1b, G, oseq, hbuf, bars + 32);
  // projection head
  gemm_bt<1><<<dim3(32, 4), 256, 0, stream>>>(oseq, Wp1b, 4096, 512, 2048, bp1, nullptr, proj);
  ln_relu<<<4096, 256, 0, stream>>>(proj, g2, be2, hproj);
  gemm_bt<2><<<dim3(32, 250), 256, 0, stream>>>(hproj, Wp2b, 4096, 32000, 512, bp2, nullptr, out);
}